// Round 2
// baseline (919.018 us; speedup 1.0000x reference)
//
#include <hip/hip_runtime.h>
#include <math.h>

// Decode paged attention, flash-decoding split-K.
// B=32, Hq=32, Hkv=8, G=4, D=128, page=16, max_pages=256 (T<=4096), fp32.
//
// R2: (a) page IDs for the whole chunk pre-loaded into one register/lane and
// broadcast via __shfl (v_readlane) -> KV addresses have no load dependence;
// (b) 2-deep register double-buffer prefetch (8 dwordx4 in flight/wave);
// (c) SPLITS 16->32 for ~2x active waves (E[T]=2048 leaves half the splits
// empty); (d) empty splits write only m/l -- reducer weight exp(NEG-M)=0
// zeroes the poison acc (0xAAAAAAAA is a finite float, 0*finite==0).

#define NUM_B    32
#define HQ       32
#define HKV      8
#define GG       4
#define DD       128
#define PAGE     16
#define MAXPAGES 256
#define SPLITS   32
#define CHUNK    128   // tokens per split (8 pages)

static constexpr float SCALE_F = 0.08838834764831845f; // 1/sqrt(128)
static constexpr float NEG     = -1e30f;               // finite -inf sentinel

static __device__ __forceinline__ float dot8(const float4& qa, const float4& qb,
                                             const float4& ka, const float4& kb) {
    return qa.x * ka.x + qa.y * ka.y + qa.z * ka.z + qa.w * ka.w +
           qb.x * kb.x + qb.y * kb.y + qb.z * kb.z + qb.w * kb.w;
}

// One wave per (b, kvh, split). Wave = 4 token-groups x 16 lanes.
// Lane (tg, ds): token tb+tg, D-slice [8*ds, 8*ds+8).
__global__ __launch_bounds__(64) void attn_split_kernel(
    const float* __restrict__ q,        // [B,1,HQ,DD]
    const float* __restrict__ kc,       // [8192,PAGE,HKV,DD]
    const float* __restrict__ vc,       // [8192,PAGE,HKV,DD]
    const int*   __restrict__ seqlens,  // [B]
    const int*   __restrict__ btab,     // [B,MAXPAGES]
    float*       __restrict__ accW,     // [B][HKV][SPLITS][GG][DD]
    float*       __restrict__ mlW)      // [B][HKV][SPLITS][GG][2]
{
    const int bid   = blockIdx.x;
    const int split = bid & (SPLITS - 1);
    const int kvh   = (bid / SPLITS) & (HKV - 1);
    const int b     = bid / (SPLITS * HKV);
    const int lane  = threadIdx.x;   // 0..63
    const int tg    = lane >> 4;     // token-group 0..3
    const int ds    = lane & 15;     // D sub-slice 0..15

    const long pbase   = ((long)(b * HKV + kvh) * SPLITS + split) * GG;
    const long accBase = pbase * DD;
    const long mlBase  = pbase * 2;

    const int T  = seqlens[b];
    const int t0 = split * CHUNK;

    if (t0 >= T) {
        // Empty partial: only m=NEG, l=0. Reducer weight exp(NEG-M)=0 kills
        // the (finite) poison acc values -> no need to zero acc.
        if (lane < GG) {
            mlW[mlBase + lane * 2]     = NEG;
            mlW[mlBase + lane * 2 + 1] = 0.f;
        }
        return;
    }

    const int t1    = min(T, t0 + CHUNK);
    const int iters = (t1 - t0 + 3) >> 2;   // <= 32

    // All page IDs of this chunk in one coalesced load (8 pages; clamp dup-loads).
    const int lastp    = (T - 1) >> 4;
    const int pidx     = min((t0 >> 4) + (lane & 15), lastp);
    const int page_reg = btab[b * MAXPAGES + pidx];

    // Q fragments: q[b, 0, kvh*G+g, 8*ds .. 8*ds+8)
    float4 q0[GG], q1[GG];
    #pragma unroll
    for (int g = 0; g < GG; ++g) {
        const float* qp = q + (long)(b * HQ + kvh * GG + g) * DD + ds * 8;
        q0[g] = *(const float4*)qp;
        q1[g] = *(const float4*)(qp + 4);
    }

    float m[GG], l[GG], acc[GG][8];
    #pragma unroll
    for (int g = 0; g < GG; ++g) {
        m[g] = NEG;
        l[g] = 0.f;
        #pragma unroll
        for (int j = 0; j < 8; ++j) acc[g][j] = 0.f;
    }

    // Address for iteration j: no memory dependence (page via v_readlane).
    auto load_iter = [&](int j, float4& k0, float4& k1, float4& v0, float4& v1) {
        j = min(j, iters - 1);                       // clamped tail prefetch (L2-hit dups)
        const int tb   = t0 + 4 * j;
        const int t    = min(tb + tg, t1 - 1);       // address-clamp, score-mask later
        const int page = __shfl(page_reg, (tb - t0) >> 4);  // uniform lane -> readlane
        const long off = (((long)page * PAGE + (t & 15)) * HKV + kvh) * DD + ds * 8;
        k0 = *(const float4*)(kc + off);
        k1 = *(const float4*)(kc + off + 4);
        v0 = *(const float4*)(vc + off);
        v1 = *(const float4*)(vc + off + 4);
    };

    auto compute = [&](int j, const float4& ck0, const float4& ck1,
                       const float4& cv0, const float4& cv1) {
        const bool valid = (t0 + 4 * j + tg) < t1;
        #pragma unroll
        for (int g = 0; g < GG; ++g) {
            float s = dot8(q0[g], q1[g], ck0, ck1);
            s += __shfl_xor(s, 1);
            s += __shfl_xor(s, 2);
            s += __shfl_xor(s, 4);
            s += __shfl_xor(s, 8);
            s = valid ? s * SCALE_F : NEG;
            const float mn    = fmaxf(m[g], s);
            const float alpha = __expf(m[g] - mn);
            const float p     = valid ? __expf(s - mn) : 0.f;
            l[g] = l[g] * alpha + p;
            m[g] = mn;
            acc[g][0] = acc[g][0] * alpha + p * cv0.x;
            acc[g][1] = acc[g][1] * alpha + p * cv0.y;
            acc[g][2] = acc[g][2] * alpha + p * cv0.z;
            acc[g][3] = acc[g][3] * alpha + p * cv0.w;
            acc[g][4] = acc[g][4] * alpha + p * cv1.x;
            acc[g][5] = acc[g][5] * alpha + p * cv1.y;
            acc[g][6] = acc[g][6] * alpha + p * cv1.z;
            acc[g][7] = acc[g][7] * alpha + p * cv1.w;
        }
    };

    // 2-deep register double-buffer: 8 dwordx4 outstanding per wave.
    float4 ka0, ka1, va0, va1, kb0, kb1, vb0, vb1;
    load_iter(0, ka0, ka1, va0, va1);
    load_iter(1, kb0, kb1, vb0, vb1);

    int i = 0;
    for (; i + 1 < iters; i += 2) {
        {
            const float4 c0 = ka0, c1 = ka1, c2 = va0, c3 = va1;
            load_iter(i + 2, ka0, ka1, va0, va1);
            compute(i, c0, c1, c2, c3);
        }
        {
            const float4 c0 = kb0, c1 = kb1, c2 = vb0, c3 = vb1;
            load_iter(i + 3, kb0, kb1, vb0, vb1);
            compute(i + 1, c0, c1, c2, c3);
        }
    }
    if (i < iters) compute(i, ka0, ka1, va0, va1);

    // Merge the 4 token-group states (lane bits 4..5) and store one partial.
    #pragma unroll
    for (int g = 0; g < GG; ++g) {
        float M2 = m[g];
        M2 = fmaxf(M2, __shfl_xor(M2, 16));
        M2 = fmaxf(M2, __shfl_xor(M2, 32));
        const float alpha = __expf(m[g] - M2);
        float lg = l[g] * alpha;
        lg += __shfl_xor(lg, 16);
        lg += __shfl_xor(lg, 32);
        float a[8];
        #pragma unroll
        for (int j = 0; j < 8; ++j) {
            float x = acc[g][j] * alpha;
            x += __shfl_xor(x, 16);
            x += __shfl_xor(x, 32);
            a[j] = x;
        }
        if (tg == 0) {
            *(float4*)(accW + accBase + g * DD + ds * 8)     = make_float4(a[0], a[1], a[2], a[3]);
            *(float4*)(accW + accBase + g * DD + ds * 8 + 4) = make_float4(a[4], a[5], a[6], a[7]);
            if (ds == 0) {
                mlW[mlBase + g * 2]     = M2;
                mlW[mlBase + g * 2 + 1] = lg;
            }
        }
    }
}

// Combine SPLITS partials per (b, kvh, g). One block per (b,kvh,g), 128 threads (d).
__global__ __launch_bounds__(128) void attn_reduce_kernel(
    const float* __restrict__ accW,
    const float* __restrict__ mlW,
    float*       __restrict__ out)   // [B, HQ, DD]
{
    const int bid = blockIdx.x;          // B*HKV*GG = 1024
    const int g   = bid & 3;
    const int kvh = (bid >> 2) & 7;
    const int b   = bid >> 5;
    const int d   = threadIdx.x;

    const long base = (long)(b * HKV + kvh) * SPLITS * GG;

    float ms[SPLITS], ls[SPLITS];
    float M = NEG;
    #pragma unroll
    for (int s = 0; s < SPLITS; ++s) {
        ms[s] = mlW[(base + s * GG + g) * 2];
        ls[s] = mlW[(base + s * GG + g) * 2 + 1];
        M = fmaxf(M, ms[s]);
    }
    float L = 0.f, o = 0.f;
    #pragma unroll
    for (int s = 0; s < SPLITS; ++s) {
        const float w = __expf(ms[s] - M);   // empty split: w==0, kills poison acc
        L += ls[s] * w;
        o += w * accW[(base + s * GG + g) * DD + d];
    }
    out[(long)(b * HQ + kvh * GG + g) * DD + d] = o / L;
}

extern "C" void kernel_launch(void* const* d_in, const int* in_sizes, int n_in,
                              void* d_out, int out_size, void* d_ws, size_t ws_size,
                              hipStream_t stream)
{
    const float* q       = (const float*)d_in[0];
    const float* kc      = (const float*)d_in[1];
    const float* vc      = (const float*)d_in[2];
    const int*   seqlens = (const int*)d_in[3];
    const int*   btab    = (const int*)d_in[4];
    float*       out     = (float*)d_out;

    // Workspace: acc partials (16.8 MB) + m/l partials (262 KB).
    float* accW = (float*)d_ws;
    float* mlW  = accW + (size_t)NUM_B * HKV * SPLITS * GG * DD;

    attn_split_kernel<<<NUM_B * HKV * SPLITS, 64, 0, stream>>>(
        q, kc, vc, seqlens, btab, accW, mlW);
    attn_reduce_kernel<<<NUM_B * HKV * GG, DD, 0, stream>>>(accW, mlW, out);
}